// Round 9
// baseline (198.407 us; speedup 1.0000x reference)
//
#include <hip/hip_runtime.h>
#include <math.h>

#define T_STEPS 32
#define BATCH 64

// ws layout (floats)
#define WS_WHQ 4096     // [8][512]
#define WS_U   8208     // 128 matrices * 8 floats (id = wv*32 + gl*16 + d*8 + w)
#define WS_XQ  9232     // [32*64][8]

typedef float v2f __attribute__((ext_vector_type(2)));
typedef unsigned int u32x2 __attribute__((ext_vector_type(2)));

struct c32 { float x, y; };
__device__ __forceinline__ c32 cmul(c32 a, c32 b){ return {a.x*b.x - a.y*b.y, a.x*b.y + a.y*b.x}; }
__device__ __forceinline__ c32 cadd(c32 a, c32 b){ return {a.x+b.x, a.y+b.y}; }

__device__ __forceinline__ v2f mkv(float x, float y){ v2f r; r.x = x; r.y = y; return r; }
__device__ __forceinline__ v2f cmulv(v2f a, v2f b){
    return mkv(a.x, a.x) * b + mkv(-a.y, a.y) * mkv(b.y, b.x);
}
__device__ __forceinline__ float fast_sigmoid(float x){ return 1.f/(1.f + __expf(-x)); }
__device__ __forceinline__ float fast_tanh(float x){ float e = __expf(2.f*x); return 1.f - 2.f/(e+1.f); }

template<int C> __device__ __forceinline__ float dppf(float v){
    return __int_as_float(__builtin_amdgcn_mov_dpp(__float_as_int(v), C, 0xF, 0xF, true));
}
__device__ __forceinline__ float swap16(float v, int lane){
#if __has_builtin(__builtin_amdgcn_permlane16_swap)
    u32x2 r = __builtin_amdgcn_permlane16_swap(__float_as_uint(v), __float_as_uint(v), false, false);
    return __uint_as_float((lane & 16) ? r.x : r.y);
#else
    return __shfl_xor(v, 16);
#endif
}
__device__ __forceinline__ float swap32(float v, int lane){
#if __has_builtin(__builtin_amdgcn_permlane32_swap)
    u32x2 r = __builtin_amdgcn_permlane32_swap(__float_as_uint(v), __float_as_uint(v), false, false);
    return __uint_as_float((lane & 32) ? r.x : r.y);
#else
    return __shfl_xor(v, 32);
#endif
}
template<int LM> __device__ __forceinline__ float lanexor(float v, int lane){
    if constexpr (LM == 1)       return dppf<0xB1>(v);
    else if constexpr (LM == 2)  return dppf<0x4E>(v);
    else if constexpr (LM == 4)  return dppf<0x1B>(dppf<0x141>(v));
    else if constexpr (LM == 8)  return dppf<0x128>(v);
    else if constexpr (LM == 16) return swap16(v, lane);
    else                         return swap32(v, lane);
}
__device__ __forceinline__ float rdl(float v, int l){
    return __int_as_float(__builtin_amdgcn_readlane(__float_as_int(v), l));
}
__device__ __forceinline__ void fsincos(float rev, float* s, float* c){
#if __has_builtin(__builtin_amdgcn_sinf) && __has_builtin(__builtin_amdgcn_cosf)
    *s = __builtin_amdgcn_sinf(rev);   // HW: sin(rev * 2pi)
    *c = __builtin_amdgcn_cosf(rev);
#else
    __sincosf(rev * 6.2831853071795864f, s, c);
#endif
}

// SoA cross-lane stage: amps packed (s0,s1) / (s2,s3); A,B per-lane complex consts
template<int LM>
__device__ __forceinline__ void stage2(v2f& X01, v2f& Y01, v2f& X23, v2f& Y23,
                                       v2f A, v2f B, int lane){
    v2f pX01 = mkv(lanexor<LM>(X01.x, lane), lanexor<LM>(X01.y, lane));
    v2f pY01 = mkv(lanexor<LM>(Y01.x, lane), lanexor<LM>(Y01.y, lane));
    v2f pX23 = mkv(lanexor<LM>(X23.x, lane), lanexor<LM>(X23.y, lane));
    v2f pY23 = mkv(lanexor<LM>(Y23.x, lane), lanexor<LM>(Y23.y, lane));
    v2f nX01 = A.x*X01 - A.y*Y01 + B.x*pX01 - B.y*pY01;
    v2f nY01 = A.x*Y01 + A.y*X01 + B.x*pY01 + B.y*pX01;
    v2f nX23 = A.x*X23 - A.y*Y23 + B.x*pX23 - B.y*pY23;
    v2f nY23 = A.x*Y23 + A.y*X23 + B.x*pY23 + B.y*pX23;
    X01 = nX01; Y01 = nY01; X23 = nX23; Y23 = nY23;
}

// One kernel, three disjoint block roles (no inter-block dependencies):
//   blocks [0,2048): Xq rows (unfolded path, no dependency on the fold)
//   blocks [2048,2064): Whq fold
//   block 2064: U matrices
__global__ void prep_kernel(const float* __restrict__ inputs,
                            const float* __restrict__ W_proj,
                            const float* __restrict__ b_proj,
                            const float* __restrict__ W_toq,
                            const float* __restrict__ fP, const float* __restrict__ iP,
                            const float* __restrict__ gP, const float* __restrict__ oP,
                            float* __restrict__ ws)
{
    int blk = blockIdx.x;
    int tid = threadIdx.x;
    if (blk < 2048) {
        __shared__ float xs[512];
        __shared__ float sproj[64];
        int row = blk;  // t*64 + b
        xs[tid]       = inputs[row * 512 + tid];
        xs[tid + 256] = inputs[row * 512 + 256 + tid];
        __syncthreads();
        int p = tid >> 2, r = tid & 3;
        const float* wp = W_proj + p * 1024 + r;
        float acc = 0.f;
        #pragma unroll 8
        for (int k = 0; k < 128; ++k) acc += xs[r + 4 * k] * wp[4 * k];
        acc += lanexor<1>(acc, tid & 63);
        acc += lanexor<2>(acc, tid & 63);
        if (r == 0) sproj[p] = acc + b_proj[p];
        __syncthreads();
        if (tid < 64) {
            int q = tid >> 3, j = tid & 7;
            const float* tq = W_toq + q * 64 + j * 8;
            const float* sp = sproj + j * 8;
            float a = 0.f;
            #pragma unroll
            for (int i = 0; i < 8; ++i) a += tq[i] * sp[i];
            a += lanexor<1>(a, tid);
            a += lanexor<2>(a, tid);
            a += lanexor<4>(a, tid);
            if (j == 0) ws[WS_XQ + row * 8 + q] = a;
        }
    } else if (blk < 2064) {
        int idx = (blk - 2048) * 256 + tid;   // 0..4095
        int q = idx >> 9, j = idx & 511;
        float acc = 0.f;
        for (int p = 0; p < 64; ++p)
            acc += W_toq[q * 64 + p] * W_proj[p * 1024 + 512 + j];
        ws[WS_WHQ + q * 512 + j] = acc;
    } else if (tid < 128) {
        int gt = tid >> 5, rest = tid & 31;
        const float* P = (gt == 0) ? fP : (gt == 1) ? iP : (gt == 2) ? gP : oP;
        int g = (rest >> 4) & 1, d = (rest >> 3) & 1, w = rest & 7;
        const float* p3 = P + (((g * 2 + d) * 8 + w) * 3);
        float a = 0.5f * p3[0], b = 0.5f * p3[1], c = 0.5f * p3[2];
        float ca = cosf(a), sa = sinf(a);
        float cb = cosf(b), sb = sinf(b);
        float cc = cosf(c), sc = sinf(c);
        c32 eb  = {cb, -sb};
        c32 ebc = {cb,  sb};
        c32 scx = {0.f, -sc};
        c32 m00 = { eb.x * ca,  eb.y * ca};
        c32 m01 = {-eb.x * sa, -eb.y * sa};
        c32 m10 = { ebc.x * sa, ebc.y * sa};
        c32 m11 = { ebc.x * ca, ebc.y * ca};
        c32 U00 = cadd(c32{cc * m00.x, cc * m00.y}, cmul(scx, m10));
        c32 U01 = cadd(c32{cc * m01.x, cc * m01.y}, cmul(scx, m11));
        c32 U10 = cadd(cmul(scx, m00), c32{cc * m10.x, cc * m10.y});
        c32 U11 = cadd(cmul(scx, m01), c32{cc * m11.x, cc * m11.y});
        float* dst = ws + WS_U + tid * 8;
        dst[0] = U00.x; dst[1] = U00.y; dst[2] = U01.x; dst[3] = U01.y;
        dst[4] = U10.x; dst[5] = U10.y; dst[6] = U11.x; dst[7] = U11.y;
    }
}

__global__ __launch_bounds__(256, 1)
void recurrence_kernel(const float* __restrict__ W_q2h,
                       const float* __restrict__ ws,
                       float* __restrict__ out)
{
    __shared__ __align__(16) float sU[1024];
    __shared__ __align__(16) float sXq[T_STEPS * 8];
    __shared__ __align__(16) float sexpW[4][8];   // [gate][q]
    __shared__ __align__(16) float qpartW[4][8];  // [gate][q]
    __shared__ __align__(16) float sH[T_STEPS * 512];  // h history (64 KB)

    int tid = threadIdx.x;   // 256
    int b   = blockIdx.x;    // 64
    int wv  = tid >> 6;
    int lane = tid & 63;
    int l = lane;

    for (int i = tid; i < 1024; i += 256) sU[i] = ws[WS_U + i];
    sXq[tid] = ws[WS_XQ + ((tid >> 3) * 64 + b) * 8 + (tid & 7)];
    if (tid < 32) ((float*)qpartW)[tid] = 0.f;

    // register-resident weights
    v2f wha2[4], whb2[4];
    #pragma unroll
    for (int j = 0; j < 4; ++j) {
        wha2[j] = mkv(ws[WS_WHQ + (2*j) * 512 + tid],       ws[WS_WHQ + (2*j+1) * 512 + tid]);
        whb2[j] = mkv(ws[WS_WHQ + (2*j) * 512 + tid + 256], ws[WS_WHQ + (2*j+1) * 512 + tid + 256]);
    }
    v2f w2hp[8];   // (W_q2h[tid][q], W_q2h[tid+256][q])
    {
        float4 a0 = *(const float4*)&W_q2h[tid * 8];
        float4 a1 = *(const float4*)&W_q2h[tid * 8 + 4];
        float4 b0 = *(const float4*)&W_q2h[(tid + 256) * 8];
        float4 b1 = *(const float4*)&W_q2h[(tid + 256) * 8 + 4];
        w2hp[0] = mkv(a0.x, b0.x); w2hp[1] = mkv(a0.y, b0.y);
        w2hp[2] = mkv(a0.z, b0.z); w2hp[3] = mkv(a0.w, b0.w);
        w2hp[4] = mkv(a1.x, b1.x); w2hp[5] = mkv(a1.y, b1.y);
        w2hp[6] = mkv(a1.z, b1.z); w2hp[7] = mkv(a1.w, b1.w);
    }

    // Gray-map bits
    int mbq[6];
    mbq[0] = (l >> 5) & 1;
    mbq[1] = ((l >> 4) ^ (l >> 5)) & 1;
    mbq[2] = ((l >> 3) ^ (l >> 4)) & 1;
    mbq[3] = ((l >> 2) ^ (l >> 3)) & 1;
    mbq[4] = ((l >> 1) ^ (l >> 2)) & 1;
    mbq[5] = (l ^ (l >> 1)) & 1;
    int l0 = l & 1;

    __syncthreads();

    // hoisted per-lane circuit constants (t-invariant)
    v2f gA[2][6], gB[2][6];
    v2f A6X[2], B6X[2], A6Y[2], B6Y[2];
    v2f A7X[2], B7X[2], A7Y[2], B7Y[2], A7Xr[2], B7Xr[2], A7Yr[2], B7Yr[2];
    v2f dA[2][6], dB[2][6];
    v2f i6m[2][4];
    v2f I7X0[2], I7Y0[2], I7X1[2], I7Y1[2];
    {
        const float* Ub = sU + wv * 256;
        #pragma unroll
        for (int gl = 0; gl < 2; ++gl) {
            const float* d0 = Ub + gl * 128;
            const float* d1 = Ub + gl * 128 + 64;
            #pragma unroll
            for (int q = 0; q < 6; ++q) {
                const float* m = d0 + q * 8;
                v2f P0 = mkv(m[0], m[1]), P1 = mkv(m[3], -m[2]);
                v2f Q0 = mkv(m[4], m[5]), Q1 = mkv(m[7], -m[6]);
                gA[gl][q] = mbq[q] ? Q0 : P0;
                gB[gl][q] = mbq[q] ? Q1 : P1;
            }
            {
                const float* m = d0 + 48;  // q6
                v2f P0 = mkv(m[0], m[1]), P1 = mkv(m[3], -m[2]);
                v2f Q0 = mkv(m[4], m[5]), Q1 = mkv(m[7], -m[6]);
                v2f cA = l0 ? Q0 : P0, cB = l0 ? Q1 : P1;
                v2f cC = l0 ? P0 : Q0, cD = l0 ? P1 : Q1;
                A6X[gl] = mkv(cA.x, cC.x); B6X[gl] = mkv(cB.x, cD.x);
                A6Y[gl] = mkv(cA.y, cC.y); B6Y[gl] = mkv(cB.y, cD.y);
            }
            {
                const float* m = d0 + 56;  // q7
                v2f P0 = mkv(m[0], m[1]), P1 = mkv(m[3], -m[2]);
                v2f Q0 = mkv(m[4], m[5]), Q1 = mkv(m[7], -m[6]);
                A7X[gl]  = mkv(P0.x, Q0.x); B7X[gl]  = mkv(P1.x, Q1.x);
                A7Y[gl]  = mkv(P0.y, Q0.y); B7Y[gl]  = mkv(P1.y, Q1.y);
                A7Xr[gl] = mkv(Q0.x, P0.x); B7Xr[gl] = mkv(Q1.x, P1.x);
                A7Yr[gl] = mkv(Q0.y, P0.y); B7Yr[gl] = mkv(Q1.y, P1.y);
            }
            #pragma unroll
            for (int st = 0; st < 6; ++st) {
                const float* m = d1 + st * 8;
                bool mb = (lane & (32 >> st)) != 0;
                dA[gl][st] = mb ? mkv(m[6], m[7]) : mkv(m[0], m[1]);
                dB[gl][st] = mb ? mkv(m[4], m[5]) : mkv(m[2], m[3]);
            }
            {
                const float* m = d1 + 48;  // w6
                i6m[gl][0] = mkv(m[0], m[1]); i6m[gl][1] = mkv(m[2], m[3]);
                i6m[gl][2] = mkv(m[4], m[5]); i6m[gl][3] = mkv(m[6], m[7]);
            }
            {
                const float* m = d1 + 56;  // w7
                I7X0[gl] = mkv(m[0], m[4]); I7Y0[gl] = mkv(m[1], m[5]);
                I7X1[gl] = mkv(m[2], m[6]); I7Y1[gl] = mkv(m[3], m[7]);
            }
        }
    }
    float sg[6];
    #pragma unroll
    for (int st = 0; st < 6; ++st) sg[st] = ((l >> st) & 1) ? -1.f : 1.f;

    const float REVC = 0.07957747154594767f;  // 0.5/(2*pi): hwsin(x*REVC) = sin(0.5*x)
    float c0 = 0.f, c1 = 0.f, h0 = 0.f, h1 = 0.f;

    // ================= recurrence =================
    for (int t = 0; t < T_STEPS; ++t) {
        // ---- angles (revolutions) ----
        float ang[8];
        {
            const v2f* qw = (const v2f*)qpartW;          // 16 v2f
            const v2f* xq2 = (const v2f*)&sXq[t * 8];    // 4 v2f
            #pragma unroll
            for (int j = 0; j < 4; ++j) {
                v2f s_ = ((qw[j] + qw[4 + j]) + (qw[8 + j] + qw[12 + j]) + xq2[j]) * REVC;
                ang[2 * j] = s_.x; ang[2 * j + 1] = s_.y;
            }
        }

        float e[8];
        #pragma unroll
        for (int gl = 0; gl < 2; ++gl) {
            float sh[8], ch[8];
            #pragma unroll
            for (int q = 0; q < 8; ++q) fsincos(ang[q], &sh[q], &ch[q]);

            // d=0 + Gray permutation, exits in SoA
            v2f mq0 = ch[0] * gA[gl][0] + sh[0] * gB[gl][0];
            v2f mq1 = ch[1] * gA[gl][1] + sh[1] * gB[gl][1];
            v2f mq2 = ch[2] * gA[gl][2] + sh[2] * gB[gl][2];
            v2f mq3 = ch[3] * gA[gl][3] + sh[3] * gB[gl][3];
            v2f mq4 = ch[4] * gA[gl][4] + sh[4] * gB[gl][4];
            v2f mq5 = ch[5] * gA[gl][5] + sh[5] * gB[gl][5];
            v2f t01 = cmulv(mq0, mq1), t23 = cmulv(mq2, mq3), t45 = cmulv(mq4, mq5);
            v2f Pp = cmulv(cmulv(t01, t23), t45);
            v2f U6X = ch[6] * A6X[gl] + sh[6] * B6X[gl];
            v2f U6Y = ch[6] * A6Y[gl] + sh[6] * B6Y[gl];
            v2f QX = Pp.x * U6X - Pp.y * U6Y;   // (Q0.x, Q1.x)
            v2f QY = Pp.x * U6Y + Pp.y * U6X;   // (Q0.y, Q1.y)
            v2f U7X  = ch[7] * A7X[gl]  + sh[7] * B7X[gl];
            v2f U7Y  = ch[7] * A7Y[gl]  + sh[7] * B7Y[gl];
            v2f U7Xr = ch[7] * A7Xr[gl] + sh[7] * B7Xr[gl];
            v2f U7Yr = ch[7] * A7Yr[gl] + sh[7] * B7Yr[gl];
            v2f X01 = QX.x * U7X  - QY.x * U7Y;   // (s0.x, s1.x)
            v2f Y01 = QX.x * U7Y  + QY.x * U7X;
            v2f X23 = QX.y * U7Xr - QY.y * U7Yr;  // (s2.x, s3.x)
            v2f Y23 = QX.y * U7Yr + QY.y * U7Xr;

            // d=1 cross-lane stages
            stage2<32>(X01, Y01, X23, Y23, dA[gl][0], dB[gl][0], lane);
            stage2<16>(X01, Y01, X23, Y23, dA[gl][1], dB[gl][1], lane);
            stage2<8> (X01, Y01, X23, Y23, dA[gl][2], dB[gl][2], lane);
            stage2<4> (X01, Y01, X23, Y23, dA[gl][3], dB[gl][3], lane);
            stage2<2> (X01, Y01, X23, Y23, dA[gl][4], dB[gl][4], lane);
            stage2<1> (X01, Y01, X23, Y23, dA[gl][5], dB[gl][5], lane);
            {   // w6: pack-aligned pairs (0,2),(1,3)
                v2f u00 = i6m[gl][0], u01 = i6m[gl][1], u10 = i6m[gl][2], u11 = i6m[gl][3];
                v2f nX01 = u00.x*X01 - u00.y*Y01 + u01.x*X23 - u01.y*Y23;
                v2f nY01 = u00.x*Y01 + u00.y*X01 + u01.x*Y23 + u01.y*X23;
                v2f nX23 = u10.x*X01 - u10.y*Y01 + u11.x*X23 - u11.y*Y23;
                v2f nY23 = u10.x*Y01 + u10.y*X01 + u11.x*Y23 + u11.y*X23;
                X01 = nX01; Y01 = nY01; X23 = nX23; Y23 = nY23;
            }
            {   // w7: in-pack pairs via packed columns
                float x0 = X01.x, x1 = X01.y, y0 = Y01.x, y1 = Y01.y;
                float x2 = X23.x, x3 = X23.y, y2 = Y23.x, y3 = Y23.y;
                v2f nX01 = x0*I7X0[gl] - y0*I7Y0[gl] + x1*I7X1[gl] - y1*I7Y1[gl];
                v2f nY01 = y0*I7X0[gl] + x0*I7Y0[gl] + y1*I7X1[gl] + x1*I7Y1[gl];
                v2f nX23 = x2*I7X0[gl] - y2*I7Y0[gl] + x3*I7X1[gl] - y3*I7Y1[gl];
                v2f nY23 = y2*I7X0[gl] + x2*I7Y0[gl] + y3*I7X1[gl] + x3*I7Y1[gl];
                X01 = nX01; Y01 = nY01; X23 = nX23; Y23 = nY23;
            }

            // probs + WHT (d=1 CNOT chain folded into parity signs)
            v2f P01 = X01 * X01 + Y01 * Y01;
            v2f P23 = X23 * X23 + Y23 * Y23;
            float pa = P01.x + P01.y, pb = P23.x + P23.y;
            float pc = P01.x - P01.y, pd = P23.x - P23.y;
            float w0v = pa + pb;
            float w6v = pa - pb;
            float w7v = pc - pd;
            #define WHT_STAGE(LM, ST) { float v_; \
                v_ = lanexor<LM>(w0v, lane); w0v = __builtin_fmaf(sg[ST], w0v, v_); \
                v_ = lanexor<LM>(w6v, lane); w6v = __builtin_fmaf(sg[ST], w6v, v_); \
                v_ = lanexor<LM>(w7v, lane); w7v = __builtin_fmaf(sg[ST], w7v, v_); }
            WHT_STAGE(1, 0) WHT_STAGE(2, 1) WHT_STAGE(4, 2)
            WHT_STAGE(8, 3) WHT_STAGE(16, 4) WHT_STAGE(32, 5)
            #undef WHT_STAGE
            e[0] = rdl(w0v, 32); e[1] = rdl(w0v, 48); e[2] = rdl(w0v, 56);
            e[3] = rdl(w0v, 60); e[4] = rdl(w0v, 62); e[5] = rdl(w0v, 63);
            e[6] = rdl(w6v, 63); e[7] = rdl(w7v, 63);
            if (gl == 0) {
                #pragma unroll
                for (int q = 0; q < 8; ++q) ang[q] = e[q] * REVC;
            }
        }
        if (lane == 0) {
            float4 e0; e0.x = e[0]; e0.y = e[1]; e0.z = e[2]; e0.w = e[3];
            float4 e1; e1.x = e[4]; e1.y = e[5]; e1.z = e[6]; e1.w = e[7];
            *(float4*)&sexpW[wv][0] = e0;
            *(float4*)&sexpW[wv][4] = e1;
        }
        __syncthreads();

        // ---- LSTM cell: per-gate dots with packed (h0,h1) weights ----
        {
            v2f pre[4];
            #pragma unroll
            for (int g = 0; g < 4; ++g) {
                float4 ea = *(const float4*)&sexpW[g][0];
                float4 eb2 = *(const float4*)&sexpW[g][4];
                v2f acc = ea.x * w2hp[0] + ea.y * w2hp[1] + ea.z * w2hp[2] + ea.w * w2hp[3]
                        + eb2.x * w2hp[4] + eb2.y * w2hp[5] + eb2.z * w2hp[6] + eb2.w * w2hp[7];
                pre[g] = acc;
            }
            float f0 = fast_sigmoid(pre[0].x), i0 = fast_sigmoid(pre[1].x);
            float g0 = fast_tanh(pre[2].x),    o0 = fast_sigmoid(pre[3].x);
            c0 = f0 * c0 + i0 * g0;  h0 = o0 * fast_tanh(c0);
            float f1 = fast_sigmoid(pre[0].y), i1 = fast_sigmoid(pre[1].y);
            float g1 = fast_tanh(pre[2].y),    o1 = fast_sigmoid(pre[3].y);
            c1 = f1 * c1 + i1 * g1;  h1 = o1 * fast_tanh(c1);
            sH[t * 512 + tid]       = h0;
            sH[t * 512 + tid + 256] = h1;
        }

        // ---- qpart for next step ----
        {
            v2f pp[4];
            #pragma unroll
            for (int j = 0; j < 4; ++j) pp[j] = wha2[j] * h0 + whb2[j] * h1;
            #pragma unroll
            for (int j = 0; j < 4; ++j) {
                pp[j] += mkv(lanexor<1>(pp[j].x, lane), lanexor<1>(pp[j].y, lane));
                pp[j] += mkv(lanexor<2>(pp[j].x, lane), lanexor<2>(pp[j].y, lane));
                pp[j] += mkv(lanexor<4>(pp[j].x, lane), lanexor<4>(pp[j].y, lane));
            }
            int sel = lane & 7;
            float y = (sel == 0) ? pp[0].x : (sel == 1) ? pp[0].y
                    : (sel == 2) ? pp[1].x : (sel == 3) ? pp[1].y
                    : (sel == 4) ? pp[2].x : (sel == 5) ? pp[2].y
                    : (sel == 6) ? pp[3].x : pp[3].y;
            y += lanexor<8>(y, lane);
            y += swap16(y, lane);
            y += swap32(y, lane);
            if (lane < 8) qpartW[wv][lane] = y;
        }
        __syncthreads();
    }

    // bulk h-history copy + final hx, cx
    {
        const float4* src = (const float4*)sH;
        float4* dst = (float4*)out;
        #pragma unroll
        for (int k = 0; k < 16; ++k) {
            int i = k * 256 + tid;          // float4 index, 4096 total
            int t = i >> 7, h4 = i & 127;
            dst[(t * 64 + b) * 128 + h4] = src[i];
        }
    }
    float* hx_out = out + (size_t)T_STEPS * 64 * 512;
    float* cx_out = hx_out + 64 * 512;
    hx_out[b * 512 + tid]       = h0;
    hx_out[b * 512 + tid + 256] = h1;
    cx_out[b * 512 + tid]       = c0;
    cx_out[b * 512 + tid + 256] = c1;
}

extern "C" void kernel_launch(void* const* d_in, const int* in_sizes, int n_in,
                              void* d_out, int out_size, void* d_ws, size_t ws_size,
                              hipStream_t stream)
{
    const float* inputs = (const float*)d_in[0];
    const float* W_proj = (const float*)d_in[1];
    const float* b_proj = (const float*)d_in[2];
    const float* W_toq  = (const float*)d_in[3];
    const float* W_q2h  = (const float*)d_in[4];
    const float* fP     = (const float*)d_in[5];
    const float* iP     = (const float*)d_in[6];
    const float* gP     = (const float*)d_in[7];
    const float* oP     = (const float*)d_in[8];
    float* ws  = (float*)d_ws;
    float* out = (float*)d_out;

    prep_kernel<<<2065, 256, 0, stream>>>(inputs, W_proj, b_proj, W_toq,
                                          fP, iP, gP, oP, ws);
    recurrence_kernel<<<BATCH, 256, 0, stream>>>(W_q2h, ws, out);
}

// Round 10
// 150.536 us; speedup vs baseline: 1.3180x; 1.3180x over previous
//
#include <hip/hip_runtime.h>
#include <math.h>

#define T_STEPS 32
#define BATCH 64

// ws layout (floats)
#define WS_WXQ 0        // [8][512]
#define WS_WHQ 4096     // [8][512]
#define WS_BQ  8192     // [8]
#define WS_U   8208     // 128 matrices * 8 floats (id = wv*32 + gl*16 + d*8 + w)
#define WS_XQ  9232     // [32*64][8]
#define WS_AB  25616    // 8 combos * (A 256 cplx + B 256 cplx) = 8*1024 floats

typedef float v2f __attribute__((ext_vector_type(2)));
typedef unsigned int u32x2 __attribute__((ext_vector_type(2)));
typedef __fp16 half4v __attribute__((ext_vector_type(4)));
typedef float f32x4 __attribute__((ext_vector_type(4)));

struct c32 { float x, y; };
__device__ __forceinline__ c32 cmul(c32 a, c32 b){ return {a.x*b.x - a.y*b.y, a.x*b.y + a.y*b.x}; }
__device__ __forceinline__ c32 cadd(c32 a, c32 b){ return {a.x+b.x, a.y+b.y}; }

__device__ __forceinline__ v2f mkv(float x, float y){ v2f r; r.x = x; r.y = y; return r; }
__device__ __forceinline__ v2f cmulv(v2f a, v2f b){
    return mkv(a.x, a.x) * b + mkv(-a.y, a.y) * mkv(b.y, b.x);
}
__device__ __forceinline__ float fast_sigmoid(float x){ return 1.f/(1.f + __expf(-x)); }
__device__ __forceinline__ float fast_tanh(float x){ float e = __expf(2.f*x); return 1.f - 2.f/(e+1.f); }

template<int C> __device__ __forceinline__ float dppf(float v){
    return __int_as_float(__builtin_amdgcn_mov_dpp(__float_as_int(v), C, 0xF, 0xF, true));
}
__device__ __forceinline__ float swap16(float v, int lane){
#if __has_builtin(__builtin_amdgcn_permlane16_swap)
    u32x2 r = __builtin_amdgcn_permlane16_swap(__float_as_uint(v), __float_as_uint(v), false, false);
    return __uint_as_float((lane & 16) ? r.x : r.y);
#else
    return __shfl_xor(v, 16);
#endif
}
__device__ __forceinline__ float swap32(float v, int lane){
#if __has_builtin(__builtin_amdgcn_permlane32_swap)
    u32x2 r = __builtin_amdgcn_permlane32_swap(__float_as_uint(v), __float_as_uint(v), false, false);
    return __uint_as_float((lane & 32) ? r.x : r.y);
#else
    return __shfl_xor(v, 32);
#endif
}
template<int LM> __device__ __forceinline__ float lanexor(float v, int lane){
    if constexpr (LM == 1)       return dppf<0xB1>(v);
    else if constexpr (LM == 2)  return dppf<0x4E>(v);
    else if constexpr (LM == 4)  return dppf<0x1B>(dppf<0x141>(v));
    else if constexpr (LM == 8)  return dppf<0x128>(v);
    else if constexpr (LM == 16) return swap16(v, lane);
    else                         return swap32(v, lane);
}
__device__ __forceinline__ float rdl(float v, int l){
    return __int_as_float(__builtin_amdgcn_readlane(__float_as_int(v), l));
}
__device__ __forceinline__ void fsincos(float rev, float* s, float* c){
#if __has_builtin(__builtin_amdgcn_sinf) && __has_builtin(__builtin_amdgcn_cosf)
    *s = __builtin_amdgcn_sinf(rev);
    *c = __builtin_amdgcn_cosf(rev);
#else
    __sincosf(rev * 6.2831853071795864f, s, c);
#endif
}

__device__ __forceinline__ void rot_u(const float* p3, float* dst){
    float a = 0.5f * p3[0], b = 0.5f * p3[1], c = 0.5f * p3[2];
    float ca = cosf(a), sa = sinf(a);
    float cb = cosf(b), sb = sinf(b);
    float cc = cosf(c), sc = sinf(c);
    c32 eb  = {cb, -sb};
    c32 ebc = {cb,  sb};
    c32 scx = {0.f, -sc};
    c32 m00 = { eb.x * ca,  eb.y * ca};
    c32 m01 = {-eb.x * sa, -eb.y * sa};
    c32 m10 = { ebc.x * sa, ebc.y * sa};
    c32 m11 = { ebc.x * ca, ebc.y * ca};
    c32 U00 = cadd(c32{cc * m00.x, cc * m00.y}, cmul(scx, m10));
    c32 U01 = cadd(c32{cc * m01.x, cc * m01.y}, cmul(scx, m11));
    c32 U10 = cadd(cmul(scx, m00), c32{cc * m10.x, cc * m10.y});
    c32 U11 = cadd(cmul(scx, m01), c32{cc * m11.x, cc * m11.y});
    dst[0] = U00.x; dst[1] = U00.y; dst[2] = U01.x; dst[3] = U01.y;
    dst[4] = U10.x; dst[5] = U10.y; dst[6] = U11.x; dst[7] = U11.y;
}

// blocks 0..31: Wxq/Whq fold; block 32: U matrices; blocks 33..40: Kronecker A/B
__global__ void precompute_kernel(const float* __restrict__ W_proj,
                                  const float* __restrict__ b_proj,
                                  const float* __restrict__ W_toq,
                                  const float* __restrict__ fP, const float* __restrict__ iP,
                                  const float* __restrict__ gP, const float* __restrict__ oP,
                                  float* __restrict__ ws)
{
    int tid = threadIdx.x;
    int blk = blockIdx.x;
    if (blk < 32) {
        int idx = blk * 256 + tid;
        int q = idx >> 10, dd = idx & 1023;
        float acc = 0.f;
        for (int p = 0; p < 64; ++p) acc += W_toq[q * 64 + p] * W_proj[p * 1024 + dd];
        if (dd < 512) ws[WS_WXQ + q * 512 + dd] = acc;
        else          ws[WS_WHQ + q * 512 + (dd - 512)] = acc;
        if (idx < 8) {
            float a2 = 0.f;
            for (int p = 0; p < 64; ++p) a2 += W_toq[idx * 64 + p] * b_proj[p];
            ws[WS_BQ + idx] = a2;
        }
    } else if (blk == 32) {
        if (tid < 128) {
            int gt = tid >> 5, rest = tid & 31;
            const float* P = (gt == 0) ? fP : (gt == 1) ? iP : (gt == 2) ? gP : oP;
            int g = (rest >> 4) & 1, d = (rest >> 3) & 1, w = rest & 7;
            rot_u(P + (((g * 2 + d) * 8 + w) * 3), ws + WS_U + tid * 8);
        }
    } else {
        // Kronecker pair matrices for combo = (gt*2+gl)
        __shared__ float sW[8][8];
        int combo = blk - 33;
        int gt = combo >> 1, gl = combo & 1;
        if (tid < 8) {
            const float* P = (gt == 0) ? fP : (gt == 1) ? iP : (gt == 2) ? gP : oP;
            rot_u(P + (((gl * 2 + 1) * 8 + tid) * 3), &sW[tid][0]);  // d=1, wire tid
        }
        __syncthreads();
        int rp = tid >> 4, rr = tid & 15;
        // A[r'][r] = prod_{w=0..3} W_w[bit_{3-w}(r')][bit_{3-w}(r)]
        c32 pa = {1.f, 0.f};
        #pragma unroll
        for (int w = 0; w < 4; ++w) {
            int i = (rp >> (3 - w)) & 1, j = (rr >> (3 - w)) & 1;
            c32 e = {sW[w][(i * 2 + j) * 2], sW[w][(i * 2 + j) * 2 + 1]};
            pa = cmul(pa, e);
        }
        ws[WS_AB + combo * 1024 + tid * 2]     = pa.x;
        ws[WS_AB + combo * 1024 + tid * 2 + 1] = pa.y;
        // B[c'][c] = prod_{w=4..7} W_w[bit_{7-w}(c')][bit_{7-w}(c)]
        c32 pb = {1.f, 0.f};
        #pragma unroll
        for (int w = 4; w < 8; ++w) {
            int i = (rp >> (7 - w)) & 1, j = (rr >> (7 - w)) & 1;
            c32 e = {sW[w][(i * 2 + j) * 2], sW[w][(i * 2 + j) * 2 + 1]};
            pb = cmul(pb, e);
        }
        ws[WS_AB + combo * 1024 + 512 + tid * 2]     = pb.x;
        ws[WS_AB + combo * 1024 + 512 + tid * 2 + 1] = pb.y;
    }
}

__global__ void xq_kernel(const float* __restrict__ inputs, float* __restrict__ ws)
{
    __shared__ float xs[512];
    int row = blockIdx.x;           // t*64 + b
    int tid = threadIdx.x;          // 256
    xs[tid]       = inputs[row * 512 + tid];
    xs[tid + 256] = inputs[row * 512 + 256 + tid];
    __syncthreads();
    int g = tid >> 5, j = tid & 31;
    const float* w = ws + WS_WXQ + g * 512;
    float acc = 0.f;
    #pragma unroll 4
    for (int i = 0; i < 16; ++i) acc += xs[j + 32 * i] * w[j + 32 * i];
    acc += __shfl_xor(acc, 1);  acc += __shfl_xor(acc, 2);
    acc += __shfl_xor(acc, 4);  acc += __shfl_xor(acc, 8);
    acc += __shfl_xor(acc, 16);
    if (j == 0) ws[WS_XQ + row * 8 + g] = acc + ws[WS_BQ + g];
}

__global__ __launch_bounds__(256, 1)
void recurrence_kernel(const float* __restrict__ W_q2h,
                       const float* __restrict__ ws,
                       float* __restrict__ out)
{
    __shared__ __align__(16) float sU[1024];
    __shared__ __align__(16) float sXq[T_STEPS * 8];
    __shared__ __align__(16) float sexpW[4][8];
    __shared__ __align__(16) float qpartW[4][8];
    __shared__ __align__(16) float sH[T_STEPS * 512];

    int tid = threadIdx.x;   // 256
    int b   = blockIdx.x;    // 64
    int wv  = tid >> 6;
    int lane = tid & 63;
    int l = lane;

    for (int i = tid; i < 1024; i += 256) sU[i] = ws[WS_U + i];
    sXq[tid] = ws[WS_XQ + ((tid >> 3) * 64 + b) * 8 + (tid & 7)];
    if (tid < 32) ((float*)qpartW)[tid] = 0.f;

    // register-resident weights
    v2f wha2[4], whb2[4];
    #pragma unroll
    for (int j = 0; j < 4; ++j) {
        wha2[j] = mkv(ws[WS_WHQ + (2*j) * 512 + tid],       ws[WS_WHQ + (2*j+1) * 512 + tid]);
        whb2[j] = mkv(ws[WS_WHQ + (2*j) * 512 + tid + 256], ws[WS_WHQ + (2*j+1) * 512 + tid + 256]);
    }
    v2f w2hp[8];
    {
        float4 a0 = *(const float4*)&W_q2h[tid * 8];
        float4 a1 = *(const float4*)&W_q2h[tid * 8 + 4];
        float4 b0 = *(const float4*)&W_q2h[(tid + 256) * 8];
        float4 b1 = *(const float4*)&W_q2h[(tid + 256) * 8 + 4];
        w2hp[0] = mkv(a0.x, b0.x); w2hp[1] = mkv(a0.y, b0.y);
        w2hp[2] = mkv(a0.z, b0.z); w2hp[3] = mkv(a0.w, b0.w);
        w2hp[4] = mkv(a1.x, b1.x); w2hp[5] = mkv(a1.y, b1.y);
        w2hp[6] = mkv(a1.z, b1.z); w2hp[7] = mkv(a1.w, b1.w);
    }

    // MFMA fragment constants (A^T in B-op layout; B in A-op layout), f16
    half4v ArT[2], AiT[2], nAiT[2], Brf[2], Bif[2], nBif[2];
    {
        int q4 = lane >> 4, n = lane & 15;
        #pragma unroll
        for (int gl = 0; gl < 2; ++gl) {
            const float* Ab = ws + WS_AB + (wv * 2 + gl) * 1024;
            const float* Bb = Ab + 512;
            #pragma unroll
            for (int j = 0; j < 4; ++j) {
                int k = 4 * q4 + j;
                float ar = Ab[(n * 16 + k) * 2], ai = Ab[(n * 16 + k) * 2 + 1];
                float br = Bb[(n * 16 + k) * 2], bi = Bb[(n * 16 + k) * 2 + 1];
                ArT[gl][j]  = (__fp16)ar;  AiT[gl][j] = (__fp16)ai;  nAiT[gl][j] = (__fp16)(-ai);
                Brf[gl][j]  = (__fp16)br;  Bif[gl][j] = (__fp16)bi;  nBif[gl][j] = (__fp16)(-bi);
            }
        }
    }

    __syncthreads();

    // d0-build constants. State j bits: b7..b4 = lane b3..b0, b5b4(row low)=e bits... full map:
    // j = (4*(lane>>4)+e)*16 + (lane&15); Gray m = j^(j>>1):
    // m7=L5 m6=L5^L4 m5=L4^e1 m4=e1^e0 m3=e0^L3 m2=L3^L2 m1=L2^L1 m0=L1^L0
    // qubit q uses m bit (7-q): fixed-per-lane qubits {0,1,5,6,7}; e-dependent {2,3,4}
    v2f sA0[2], sB0[2], sA1[2], sB1[2], sA5[2], sB5[2], sA6[2], sB6[2], sA7[2], sB7[2];
    v2f A2a[2], B2a[2], A2b[2], B2b[2];
    v2f A3a[2], B3a[2], A3b[2], B3b[2];
    v2f A4a[2], B4a[2], A4b[2], B4b[2];
    {
        int s0 = (l >> 5) & 1;
        int s1 = ((l >> 5) ^ (l >> 4)) & 1;
        int s5 = ((l >> 3) ^ (l >> 2)) & 1;
        int s6 = ((l >> 2) ^ (l >> 1)) & 1;
        int s7 = ((l >> 1) ^ l) & 1;
        int L4 = (l >> 4) & 1;
        int L3 = (l >> 3) & 1;
        #pragma unroll
        for (int gl = 0; gl < 2; ++gl) {
            const float* d0 = sU + (wv * 32 + gl * 16) * 8;
            auto colA = [&](int q, int c){ const float* m = d0 + q * 8 + c * 4; return mkv(m[0], m[1]); };
            auto colB = [&](int q, int c){ const float* m = d0 + q * 8 + c * 4; return mkv(m[3 - c * 4 + c * 4 + 3 - 3 + 3], 0.f); };
            // (colB needs (m[3],-m[2]) pattern; write explicitly below instead of lambda trickery)
            #define CA(q,c) mkv(d0[(q)*8 + (c)*4 + 0], d0[(q)*8 + (c)*4 + 1])
            #define CB(q,c) mkv(d0[(q)*8 + (c)*4 + 3], -d0[(q)*8 + (c)*4 + 2])
            sA0[gl] = s0 ? CA(0,1) : CA(0,0);  sB0[gl] = s0 ? CB(0,1) : CB(0,0);
            sA1[gl] = s1 ? CA(1,1) : CA(1,0);  sB1[gl] = s1 ? CB(1,1) : CB(1,0);
            sA5[gl] = s5 ? CA(5,1) : CA(5,0);  sB5[gl] = s5 ? CB(5,1) : CB(5,0);
            sA6[gl] = s6 ? CA(6,1) : CA(6,0);  sB6[gl] = s6 ? CB(6,1) : CB(6,0);
            sA7[gl] = s7 ? CA(7,1) : CA(7,0);  sB7[gl] = s7 ? CB(7,1) : CB(7,0);
            A2a[gl] = L4 ? CA(2,1) : CA(2,0);  B2a[gl] = L4 ? CB(2,1) : CB(2,0);
            A2b[gl] = L4 ? CA(2,0) : CA(2,1);  B2b[gl] = L4 ? CB(2,0) : CB(2,1);
            A3a[gl] = CA(3,0);                 B3a[gl] = CB(3,0);
            A3b[gl] = CA(3,1);                 B3b[gl] = CB(3,1);
            A4a[gl] = L3 ? CA(4,1) : CA(4,0);  B4a[gl] = L3 ? CB(4,1) : CB(4,0);
            A4b[gl] = L3 ? CA(4,0) : CA(4,1);  B4b[gl] = L3 ? CB(4,0) : CB(4,1);
            #undef CA
            #undef CB
            (void)colA; (void)colB;
        }
    }
    float sg[6];
    #pragma unroll
    for (int st = 0; st < 6; ++st) sg[st] = ((l >> st) & 1) ? -1.f : 1.f;

    const float REVC = 0.07957747154594767f;
    const f32x4 zacc = {0.f, 0.f, 0.f, 0.f};
    float c0 = 0.f, c1 = 0.f, h0 = 0.f, h1 = 0.f;

    // ================= recurrence =================
    for (int t = 0; t < T_STEPS; ++t) {
        float ang[8];
        {
            const v2f* qw = (const v2f*)qpartW;
            const v2f* xq2 = (const v2f*)&sXq[t * 8];
            #pragma unroll
            for (int j = 0; j < 4; ++j) {
                v2f s_ = ((qw[j] + qw[4 + j]) + (qw[8 + j] + qw[12 + j]) + xq2[j]) * REVC;
                ang[2 * j] = s_.x; ang[2 * j + 1] = s_.y;
            }
        }

        float e[8];
        #pragma unroll
        for (int gl = 0; gl < 2; ++gl) {
            float sh[8], ch[8];
            #pragma unroll
            for (int q = 0; q < 8; ++q) fsincos(ang[q], &sh[q], &ch[q]);

            // selected d0 columns
            v2f u0 = ch[0] * sA0[gl] + sh[0] * sB0[gl];
            v2f u1 = ch[1] * sA1[gl] + sh[1] * sB1[gl];
            v2f u5 = ch[5] * sA5[gl] + sh[5] * sB5[gl];
            v2f u6 = ch[6] * sA6[gl] + sh[6] * sB6[gl];
            v2f u7 = ch[7] * sA7[gl] + sh[7] * sB7[gl];
            v2f u2a = ch[2] * A2a[gl] + sh[2] * B2a[gl];
            v2f u2b = ch[2] * A2b[gl] + sh[2] * B2b[gl];
            v2f u3a = ch[3] * A3a[gl] + sh[3] * B3a[gl];
            v2f u3b = ch[3] * A3b[gl] + sh[3] * B3b[gl];
            v2f u4a = ch[4] * A4a[gl] + sh[4] * B4a[gl];
            v2f u4b = ch[4] * A4b[gl] + sh[4] * B4b[gl];

            v2f hi = cmulv(u0, u1);
            v2f lo = cmulv(cmulv(u5, u6), u7);
            v2f hilo = cmulv(hi, lo);
            v2f u23_0 = cmulv(u2a, u3a);
            v2f u23_1 = cmulv(u2a, u3b);
            v2f u23_2 = cmulv(u2b, u3b);
            v2f u23_3 = cmulv(u2b, u3a);
            v2f mid0 = cmulv(u23_0, u4a);
            v2f mid1 = cmulv(u23_1, u4b);
            v2f mid2 = cmulv(u23_2, u4a);
            v2f mid3 = cmulv(u23_3, u4b);
            v2f a0 = cmulv(hilo, mid0);
            v2f a1 = cmulv(hilo, mid1);
            v2f a2 = cmulv(hilo, mid2);
            v2f a3 = cmulv(hilo, mid3);

            half4v Sr, Si;
            Sr[0] = (__fp16)a0.x; Sr[1] = (__fp16)a1.x; Sr[2] = (__fp16)a2.x; Sr[3] = (__fp16)a3.x;
            Si[0] = (__fp16)a0.y; Si[1] = (__fp16)a1.y; Si[2] = (__fp16)a2.y; Si[3] = (__fp16)a3.y;

            // T^T = S^T A^T (complex, 4 MFMA)
            f32x4 TrT = __builtin_amdgcn_mfma_f32_16x16x16f16(Sr, ArT[gl], zacc, 0, 0, 0);
            TrT = __builtin_amdgcn_mfma_f32_16x16x16f16(Si, nAiT[gl], TrT, 0, 0, 0);
            f32x4 TiT = __builtin_amdgcn_mfma_f32_16x16x16f16(Sr, AiT[gl], zacc, 0, 0, 0);
            TiT = __builtin_amdgcn_mfma_f32_16x16x16f16(Si, ArT[gl], TiT, 0, 0, 0);
            half4v TrH, TiH;
            #pragma unroll
            for (int j = 0; j < 4; ++j) { TrH[j] = (__fp16)TrT[j]; TiH[j] = (__fp16)TiT[j]; }
            // S'^T = B T^T (complex, 4 MFMA)
            f32x4 Xr = __builtin_amdgcn_mfma_f32_16x16x16f16(Brf[gl], TrH, zacc, 0, 0, 0);
            Xr = __builtin_amdgcn_mfma_f32_16x16x16f16(nBif[gl], TiH, Xr, 0, 0, 0);
            f32x4 Xi = __builtin_amdgcn_mfma_f32_16x16x16f16(Brf[gl], TiH, zacc, 0, 0, 0);
            Xi = __builtin_amdgcn_mfma_f32_16x16x16f16(Bif[gl], TrH, Xi, 0, 0, 0);

            // probs; final j bits: b7..b4 = lane b3..b0, b3b2 = lane b5b4, b1b0 = r
            float p0 = Xr[0]*Xr[0] + Xi[0]*Xi[0];
            float p1 = Xr[1]*Xr[1] + Xi[1]*Xi[1];
            float p2 = Xr[2]*Xr[2] + Xi[2]*Xi[2];
            float p3 = Xr[3]*Xr[3] + Xi[3]*Xi[3];
            float w0v = (p0 + p1) + (p2 + p3);
            float w6v = (p0 + p1) - (p2 + p3);   // (-1)^{j1}
            float w7v = (p0 - p1) - (p2 - p3);   // (-1)^{j1^j0}
            #define WHT_STAGE(LM, ST) { float v_; \
                v_ = lanexor<LM>(w0v, lane); w0v = __builtin_fmaf(sg[ST], w0v, v_); \
                v_ = lanexor<LM>(w6v, lane); w6v = __builtin_fmaf(sg[ST], w6v, v_); \
                v_ = lanexor<LM>(w7v, lane); w7v = __builtin_fmaf(sg[ST], w7v, v_); }
            WHT_STAGE(1, 0) WHT_STAGE(2, 1) WHT_STAGE(4, 2)
            WHT_STAGE(8, 3) WHT_STAGE(16, 4) WHT_STAGE(32, 5)
            #undef WHT_STAGE
            // e[q]: masks — e0:{L3}=8 e1:{L3,L2}=12 e2:+L1=14 e3:+L0=15 e4:+L5=47 e5:+L4=63
            e[0] = rdl(w0v, 8);  e[1] = rdl(w0v, 12); e[2] = rdl(w0v, 14);
            e[3] = rdl(w0v, 15); e[4] = rdl(w0v, 47); e[5] = rdl(w0v, 63);
            e[6] = rdl(w6v, 63); e[7] = rdl(w7v, 63);
            if (gl == 0) {
                #pragma unroll
                for (int q = 0; q < 8; ++q) ang[q] = e[q] * REVC;
            }
        }
        if (lane == 0) {
            float4 e0v; e0v.x = e[0]; e0v.y = e[1]; e0v.z = e[2]; e0v.w = e[3];
            float4 e1v; e1v.x = e[4]; e1v.y = e[5]; e1v.z = e[6]; e1v.w = e[7];
            *(float4*)&sexpW[wv][0] = e0v;
            *(float4*)&sexpW[wv][4] = e1v;
        }
        __syncthreads();

        // ---- LSTM cell ----
        {
            v2f pre[4];
            #pragma unroll
            for (int g = 0; g < 4; ++g) {
                float4 ea = *(const float4*)&sexpW[g][0];
                float4 eb2 = *(const float4*)&sexpW[g][4];
                v2f acc = ea.x * w2hp[0] + ea.y * w2hp[1] + ea.z * w2hp[2] + ea.w * w2hp[3]
                        + eb2.x * w2hp[4] + eb2.y * w2hp[5] + eb2.z * w2hp[6] + eb2.w * w2hp[7];
                pre[g] = acc;
            }
            float f0 = fast_sigmoid(pre[0].x), i0 = fast_sigmoid(pre[1].x);
            float g0 = fast_tanh(pre[2].x),    o0 = fast_sigmoid(pre[3].x);
            c0 = f0 * c0 + i0 * g0;  h0 = o0 * fast_tanh(c0);
            float f1 = fast_sigmoid(pre[0].y), i1 = fast_sigmoid(pre[1].y);
            float g1 = fast_tanh(pre[2].y),    o1 = fast_sigmoid(pre[3].y);
            c1 = f1 * c1 + i1 * g1;  h1 = o1 * fast_tanh(c1);
            sH[t * 512 + tid]       = h0;
            sH[t * 512 + tid + 256] = h1;
        }

        // ---- qpart for next step ----
        {
            v2f pp[4];
            #pragma unroll
            for (int j = 0; j < 4; ++j) pp[j] = wha2[j] * h0 + whb2[j] * h1;
            #pragma unroll
            for (int j = 0; j < 4; ++j) {
                pp[j] += mkv(lanexor<1>(pp[j].x, lane), lanexor<1>(pp[j].y, lane));
                pp[j] += mkv(lanexor<2>(pp[j].x, lane), lanexor<2>(pp[j].y, lane));
                pp[j] += mkv(lanexor<4>(pp[j].x, lane), lanexor<4>(pp[j].y, lane));
            }
            int sel = lane & 7;
            float y = (sel == 0) ? pp[0].x : (sel == 1) ? pp[0].y
                    : (sel == 2) ? pp[1].x : (sel == 3) ? pp[1].y
                    : (sel == 4) ? pp[2].x : (sel == 5) ? pp[2].y
                    : (sel == 6) ? pp[3].x : pp[3].y;
            y += lanexor<8>(y, lane);
            y += swap16(y, lane);
            y += swap32(y, lane);
            if (lane < 8) qpartW[wv][lane] = y;
        }
        __syncthreads();
    }

    // bulk h-history copy + final hx, cx
    {
        const float4* src = (const float4*)sH;
        float4* dst = (float4*)out;
        #pragma unroll
        for (int k = 0; k < 16; ++k) {
            int i = k * 256 + tid;
            int t = i >> 7, h4 = i & 127;
            dst[(t * 64 + b) * 128 + h4] = src[i];
        }
    }
    float* hx_out = out + (size_t)T_STEPS * 64 * 512;
    float* cx_out = hx_out + 64 * 512;
    hx_out[b * 512 + tid]       = h0;
    hx_out[b * 512 + tid + 256] = h1;
    cx_out[b * 512 + tid]       = c0;
    cx_out[b * 512 + tid + 256] = c1;
}

extern "C" void kernel_launch(void* const* d_in, const int* in_sizes, int n_in,
                              void* d_out, int out_size, void* d_ws, size_t ws_size,
                              hipStream_t stream)
{
    const float* inputs = (const float*)d_in[0];
    const float* W_proj = (const float*)d_in[1];
    const float* b_proj = (const float*)d_in[2];
    const float* W_toq  = (const float*)d_in[3];
    const float* W_q2h  = (const float*)d_in[4];
    const float* fP     = (const float*)d_in[5];
    const float* iP     = (const float*)d_in[6];
    const float* gP     = (const float*)d_in[7];
    const float* oP     = (const float*)d_in[8];
    float* ws  = (float*)d_ws;
    float* out = (float*)d_out;

    precompute_kernel<<<41, 256, 0, stream>>>(W_proj, b_proj, W_toq, fP, iP, gP, oP, ws);
    xq_kernel<<<T_STEPS * BATCH, 256, 0, stream>>>(inputs, ws);
    recurrence_kernel<<<BATCH, 256, 0, stream>>>(W_q2h, ws, out);
}